// Round 9
// baseline (321.214 us; speedup 1.0000x reference)
//
#include <hip/hip_runtime.h>

typedef unsigned short u16;
typedef __bf16 bf16_t;
typedef bf16_t bf16x8 __attribute__((ext_vector_type(8)));
typedef float floatx4 __attribute__((ext_vector_type(4)));
typedef float floatx16 __attribute__((ext_vector_type(16)));

static constexpr float kScale = 0.014731391274719741f;    // 1/sqrt(512*9)
static constexpr float kScale2 = 2.1701388888888894e-4f;  // 1/(512*9)
static constexpr float kLinScale = 0.044194173824159216f; // 1/sqrt(512)

__device__ __forceinline__ u16 f2bf(float f) {
  unsigned u = __float_as_uint(f);
  u += 0x7FFFu + ((u >> 16) & 1u);
  return (u16)(u >> 16);
}

// async 16B global->LDS; LDS dst semantics: wave-uniform base + lane*16
#define GLD16(g, l)                                                        \
  __builtin_amdgcn_global_load_lds(                                        \
      (const __attribute__((address_space(1))) unsigned int*)(g),          \
      (__attribute__((address_space(3))) unsigned int*)(l), 16, 0, 0)

// ---------------------------------------------------------------------------
// Fused prep: blocks [0,1024): s[b,c] = style.modw^T*lin + bias
//             blocks [1024,2048): ssq[o,c] = sum_tap w^2
__global__ __launch_bounds__(256) void k_prep1(const float* __restrict__ style,
                                               const float* __restrict__ modw,
                                               const float* __restrict__ modb,
                                               const float* __restrict__ weight,
                                               float* __restrict__ s_buf,
                                               float* __restrict__ ssq) {
  int tid = threadIdx.x;
  if (blockIdx.x < 1024) {
    int lane = tid & 63, wv = tid >> 6;
    int idx = blockIdx.x * 4 + wv; // [0,4096)
    int b = idx >> 9, c = idx & 511;
    const float* st = style + b * 512;
    const float* mw = modw + (size_t)c * 512;
    float s = 0.f;
#pragma unroll
    for (int i = 0; i < 8; ++i) s += st[lane + i * 64] * mw[lane + i * 64];
#pragma unroll
    for (int off = 32; off; off >>= 1) s += __shfl_xor(s, off);
    if (lane == 0) s_buf[idx] = s * kLinScale + modb[c];
  } else {
    int e = (blockIdx.x - 1024) * 256 + tid; // [0, 262144)
    const float* wp = weight + (size_t)e * 9;
    float ss = 0.f;
#pragma unroll
    for (int t = 0; t < 9; ++t) ss += wp[t] * wp[t];
    ssq[e] = ss;
  }
}

// ---------------------------------------------------------------------------
// demod[b,o] = rsqrt( kScale^2 * sum_c ssq[o,c]*s[b,c]^2 + eps )
__global__ __launch_bounds__(256) void k_demod2(const float* __restrict__ ssq,
                                                const float* __restrict__ s_buf,
                                                float* __restrict__ demod_buf) {
  int tid = threadIdx.x, lane = tid & 63, wv = tid >> 6;
  int idx = blockIdx.x * 4 + wv; // [0,4096)
  int b = idx >> 9, o = idx & 511;
  const float* sq = ssq + (size_t)o * 512;
  const float* srow = s_buf + b * 512;
  float ss = 0.f;
#pragma unroll
  for (int i = 0; i < 8; ++i) {
    float s = srow[lane + i * 64];
    ss += sq[lane + i * 64] * s * s;
  }
#pragma unroll
  for (int off = 32; off; off >>= 1) ss += __shfl_xor(ss, off);
  if (lane == 0) demod_buf[idx] = rsqrtf(ss * kScale2 + 1e-8f);
}

// ---------------------------------------------------------------------------
// NCHW f32 -> NHWC bf16 with fused per-channel modulation:
// in_t[b,y,x,c] = bf16( in[b,c,y,x] * s[b,c] )
__global__ __launch_bounds__(256) void k_transpose(const float* __restrict__ in,
                                                   const float* __restrict__ s_buf,
                                                   unsigned* __restrict__ in_t32) {
  __shared__ u16 tile[64 * 65];
  int tid = threadIdx.x;
  int c0 = blockIdx.x * 64, y = blockIdx.y, b = blockIdx.z;
  const float* src = in + ((size_t)(b * 512 + c0) * 4096) + y * 64;
  const float* srow = s_buf + b * 512 + c0;
#pragma unroll
  for (int it = 0; it < 16; ++it) {
    int idx = it * 256 + tid;
    int cl = idx >> 6, x = idx & 63;
    tile[cl * 65 + x] = f2bf(src[(size_t)cl * 4096 + x] * srow[cl]);
  }
  __syncthreads();
  unsigned* dst = in_t32 + ((size_t)(b * 64 + y) * 64) * 256 + (c0 >> 1);
#pragma unroll
  for (int it = 0; it < 8; ++it) {
    int flat = it * 256 + tid; // [0,2048)
    int cl2 = flat & 31, x = flat >> 5;
    unsigned lo = tile[(2 * cl2) * 65 + x];
    unsigned hi = tile[(2 * cl2 + 1) * 65 + x];
    dst[(size_t)x * 256 + cl2] = lo | (hi << 16);
  }
}

// ---------------------------------------------------------------------------
// Weight fragments for mfma_f32_32x32x16_bf16:
// w_t[tap][ct8][ot][ks][512 u16], fragment order lane = o_l + 32*(k16>>3),
// elem = k16&7 (same lane/elem pattern as the verified 16x16x32 layout,
// scaled to M=32). o_l = o - ot*32, k16 = c - ct8*64 - ks*16. 4.5 MB.
__global__ __launch_bounds__(256) void k_wfrag(const float* __restrict__ weight,
                                               unsigned* __restrict__ wt32) {
  int tid = threadIdx.x;
  int ct8 = blockIdx.x; // [0,8)  64-ch group
  int ot = blockIdx.y;  // [0,16) 32-O tile
#pragma unroll
  for (int tap = 0; tap < 9; ++tap) {
#pragma unroll
    for (int i = 0; i < 4; ++i) {
      int f32i = i * 256 + tid;        // [0,1024) u32 per tap
      int ks = f32i >> 8;              // [0,4)
      int rem = f32i & 255;            // u32 index within 512-u16 frag
      int lane = rem >> 2;             // [0,64)
      int ep = (rem & 3) * 2;          // even element of the pair
      int o = ot * 32 + (lane & 31);
      int c = ct8 * 64 + ks * 16 + (lane >> 5) * 8 + ep;
      unsigned lo = f2bf(weight[((size_t)o * 512 + c) * 9 + tap] * kScale);
      unsigned hi = f2bf(weight[((size_t)o * 512 + c + 1) * 9 + tap] * kScale);
      wt32[((size_t)(((tap * 8 + ct8) * 16 + ot) * 4 + ks) << 8) + rem] =
          lo | (hi << 16);
    }
  }
}

// ---------------------------------------------------------------------------
// Implicit-GEMM conv, MFMA-SHAPE round. Eight rounds left a robust invariant:
// ~13.8 cyc of dead time PER MFMA INSTRUCTION issued (overhead scaled 1:1
// with instruction count R5->R6, immune to all memory/schedule changes).
// Test: v_mfma_f32_32x32x16_bf16 = same FLOPs in HALF the instructions,
// +15% ceiling (2382 vs 2075 TF). Structure = R6 exactly (K=64/t-step,
// double-buffered 64-ch B cells, zero-conflict slot=chunk8^(px&7) swizzle,
// depth-1 A/B register rings, vmcnt(8) counted barrier, XCD swizzle).
// Wave tile 64x64 = 2x2 tiles of 32x32; acc = 4 x f32x16 = 64 AGPR (same).
// B read addr: slot XOR decomposed as base + ((ks<<5) ^ ((sx&6)<<4)).
// A frag: lane = o+32*(k>>3), elem=k&7 (w_t packed accordingly).
// C/D: col=lane&31, row=(reg&3)+8*(reg>>2)+4*(lane>>5)  [m74/m101].
// Tripwires: WRITE_SIZE ~68 MB (spill), SQ_LDS_BANK_CONFLICT ~0.
__global__ __launch_bounds__(256, 2) void k_conv(const u16* __restrict__ in_t,
                                                 const u16* __restrict__ w_t,
                                                 const float* __restrict__ demod_buf,
                                                 float* __restrict__ out) {
  __shared__ char smem[67584]; // 2 buffers x (4 rows x 66 cells x 128 B)
  const int tid = threadIdx.x;
  const int lane = tid & 63;
  const int wv = tid >> 6;
  const int wm = wv >> 1, wn = wv & 1;
  const int n31 = lane & 31, h = lane >> 5;
  const int lin = blockIdx.x + 32 * blockIdx.y + 128 * blockIdx.z; // [0,1024)
  const int b = lin & 7;
  const int r_ = lin >> 3;   // [0,128)
  const int nt = r_ & 31;
  const int mt = r_ >> 5;    // [0,4)
  const int y0 = nt * 2;

  floatx16 acc[2][2];
#pragma unroll
  for (int i = 0; i < 2; ++i)
#pragma unroll
    for (int j = 0; j < 2; ++j)
#pragma unroll
      for (int r = 0; r < 16; ++r) acc[i][j][r] = 0.f;

  // B stage source (identical to R6): thread covers slot qs of cell xs.
  const int xs = tid >> 3, qs = tid & 7;
  const int cch = qs ^ (xs & 7); // global 8-ch chunk stored at slot qs
  const u16* gB[4];
  bool rok[4];
#pragma unroll
  for (int r = 0; r < 4; ++r) {
    int y = y0 - 1 + r;
    rok[r] = (unsigned)y < 64u; // block-uniform
    gB[r] = in_t + (((size_t)(b * 64 + (rok[r] ? y : 0)) * 64 + xs) * 512 + cch * 8);
  }

  const int wnrow = wn * 8448; // row base for this wave's px rows

  bf16x8 aR[2][2][4]; // [ring][mt2][ks]
  bf16x8 bv[2][2][4]; // [ring][nt2][ks]

// B fragments for tap t_ from buffer bufimm into ring slot si.
// addr = wnrow + dy*8448 + (sx+1)*128 + ((2ks+h)^(sx&7))*16, decomposed so
// the ks-varying part is ((ks<<5) ^ ((sx&6)<<4)).
#define LOAD_BV(si, bufimm, t_)                                              \
  {                                                                          \
    const int dy_ = (t_) / 3, dx_ = (t_) % 3;                                \
    _Pragma("unroll") for (int n2 = 0; n2 < 2; ++n2) {                       \
      const int sx = n2 * 32 + n31 + dx_ - 1;                                \
      char* base_ = smem + (bufimm) + wnrow + dy_ * 8448 + (sx + 1) * 128 +  \
                    ((h ^ (sx & 1)) << 4);                                   \
      const int T_ = (sx & 6) << 4;                                          \
      _Pragma("unroll") for (int ks = 0; ks < 4; ++ks)                       \
        bv[si][n2][ks] = *(const bf16x8*)(base_ + ((ks << 5) ^ T_));         \
    }                                                                        \
  }

#define STAGE_B(bufimm)                                                      \
  {                                                                          \
    _Pragma("unroll") for (int r = 0; r < 4; ++r)                            \
      if (rok[r]) {                                                          \
        GLD16(gB[r], smem + (bufimm) + r * 8448 + 128 + wv * 1024);          \
        GLD16(gB[r] + 16384,                                                 \
              smem + (bufimm) + r * 8448 + 128 + 4096 + wv * 1024);          \
      }                                                                      \
  }

// A fragments (tap tp_, 64-ch group ctp_) into ring slot si: per mt2 one
// base, ks via 1KB immediates. frag index = ((tp_*8+ctp_)*16 + ot)*4 + ks.
#define LOAD_A2(si, tp_, ctp_)                                               \
  {                                                                          \
    _Pragma("unroll") for (int mt2 = 0; mt2 < 2; ++mt2) {                    \
      const u16* ap_ =                                                       \
          w_t +                                                              \
          ((size_t)(((tp_)*8 + (ctp_)) * 16 + (mt * 4 + wm * 2 + mt2)) << 11) + \
          lane * 8;                                                          \
      _Pragma("unroll") for (int ks = 0; ks < 4; ++ks)                       \
        aR[si][mt2][ks] = *(const bf16x8*)(ap_ + ks * 512);                  \
    }                                                                        \
  }

// one ct' (64 channels): 9 tap-steps of 16 MFMA(32x32x16); A+B frag prefetch
// depth 1; stage(ct'+1) in flight across the t-loop, drained by vmcnt(8).
#define CT_BODY(ctv, par, CURIMM, NXTIMM)                                    \
  {                                                                          \
    LOAD_BV(par, CURIMM, 0);                                                 \
    if ((ctv) + 1 < 8) {                                                     \
      _Pragma("unroll") for (int r = 0; r < 4; ++r) gB[r] += 64;             \
      STAGE_B(NXTIMM);                                                       \
    }                                                                        \
    _Pragma("unroll") for (int t = 0; t < 9; ++t) {                          \
      const int icur = (t + (par)) & 1;                                      \
      const int inxt = icur ^ 1;                                             \
      const int tp = t < 8 ? t + 1 : 0;                                      \
      const int ctp = t < 8 ? (ctv) : (((ctv) + 1) & 7);                     \
      LOAD_A2(inxt, tp, ctp);                                                \
      if (t < 8) { LOAD_BV(inxt, CURIMM, t + 1); }                           \
      __builtin_amdgcn_s_setprio(1);                                         \
      _Pragma("unroll") for (int ks = 0; ks < 4; ++ks)                       \
        _Pragma("unroll") for (int mt2 = 0; mt2 < 2; ++mt2)                  \
          _Pragma("unroll") for (int nt2 = 0; nt2 < 2; ++nt2)                \
            acc[mt2][nt2] = __builtin_amdgcn_mfma_f32_32x32x16_bf16(         \
                aR[icur][mt2][ks], bv[icur][nt2][ks], acc[mt2][nt2],         \
                0, 0, 0);                                                    \
      __builtin_amdgcn_s_setprio(0);                                         \
    }                                                                        \
    asm volatile("s_waitcnt vmcnt(8)" ::: "memory");                         \
    __builtin_amdgcn_s_barrier();                                            \
  }

  // ---- prologue: zero LDS (pads + OOB rows), stage ct'=0, load A(0,0) ----
  {
    const uint4 z = make_uint4(0u, 0u, 0u, 0u);
    for (int i = tid; i < 4224; i += 256) ((uint4*)smem)[i] = z;
  }
  __syncthreads();
  STAGE_B(0);
  __syncthreads(); // drains stage(0) + makes zeros visible
  LOAD_A2(0, 0, 0);

  for (int ct = 0; ct < 8; ct += 2) {
    CT_BODY(ct, 0, 0, 33792);
    CT_BODY(ct + 1, 1, 33792, 0);
  }

#undef LOAD_BV
#undef STAGE_B
#undef LOAD_A2
#undef CT_BODY

  // epilogue: 32x32 C/D: col = lane&31 -> px, row = (r&3)+8*(r>>2)+4*h -> o.
  // px nl = wn*64 + nt2*32 + n31: y = y0 + wn, x = nt2*32 + n31.
#pragma unroll
  for (int mt2 = 0; mt2 < 2; ++mt2)
#pragma unroll
    for (int nt2 = 0; nt2 < 2; ++nt2) {
      const int x = nt2 * 32 + n31;
      const int ybase = (y0 + wn) * 64 + x;
#pragma unroll
      for (int r = 0; r < 16; ++r) {
        const int o = mt * 128 + wm * 64 + mt2 * 32 +
                      (r & 3) + 8 * (r >> 2) + 4 * h;
        float dm = demod_buf[b * 512 + o];
        out[((size_t)(b * 512 + o) << 12) + ybase] = acc[mt2][nt2][r] * dm;
      }
    }
}

// ---------------------------------------------------------------------------
extern "C" void kernel_launch(void* const* d_in, const int* in_sizes, int n_in,
                              void* d_out, int out_size, void* d_ws, size_t ws_size,
                              hipStream_t stream) {
  const float* input = (const float*)d_in[0];   // [8,512,64,64] f32
  const float* style = (const float*)d_in[1];   // [8,512] f32
  const float* weight = (const float*)d_in[2];  // [1,512,512,3,3] f32
  const float* modw = (const float*)d_in[3];    // [512,512] f32
  const float* modb = (const float*)d_in[4];    // [512] f32
  float* out = (float*)d_out;                   // [8,512,64,64] f32
  char* ws = (char*)d_ws;
  float* s_buf = (float*)ws;                             // 16 KB
  float* demod_buf = (float*)(ws + 16384);               // 16 KB
  float* ssq = (float*)(ws + 32768);                     // 1 MB
  u16* in_t = (u16*)(ws + 32768 + 1048576);              // NHWC bf16, 33.5 MB
  u16* w_t = (u16*)(ws + 32768 + 1048576 + 33554432);    // frag bf16, 4.5 MB

  k_prep1<<<dim3(2048), dim3(256), 0, stream>>>(style, modw, modb, weight, s_buf, ssq);
  k_demod2<<<dim3(1024), dim3(256), 0, stream>>>(ssq, s_buf, demod_buf);
  k_transpose<<<dim3(8, 64, 8), dim3(256), 0, stream>>>(input, s_buf, (unsigned*)in_t);
  k_wfrag<<<dim3(8, 16), dim3(256), 0, stream>>>(weight, (unsigned*)w_t);
  k_conv<<<dim3(32, 4, 8), dim3(256), 0, stream>>>(in_t, w_t, demod_buf, out);
}

// Round 10
// 243.054 us; speedup vs baseline: 1.3216x; 1.3216x over previous
//
#include <hip/hip_runtime.h>

typedef unsigned short u16;
typedef __bf16 bf16_t;
typedef bf16_t bf16x8 __attribute__((ext_vector_type(8)));
typedef float floatx4 __attribute__((ext_vector_type(4)));

static constexpr float kScale = 0.014731391274719741f;    // 1/sqrt(512*9)
static constexpr float kScale2 = 2.1701388888888894e-4f;  // 1/(512*9)
static constexpr float kLinScale = 0.044194173824159216f; // 1/sqrt(512)

__device__ __forceinline__ u16 f2bf(float f) {
  unsigned u = __float_as_uint(f);
  u += 0x7FFFu + ((u >> 16) & 1u);
  return (u16)(u >> 16);
}

// async 16B global->LDS; LDS dst semantics: wave-uniform base + lane*16
#define GLD16(g, l)                                                        \
  __builtin_amdgcn_global_load_lds(                                        \
      (const __attribute__((address_space(1))) unsigned int*)(g),          \
      (__attribute__((address_space(3))) unsigned int*)(l), 16, 0, 0)

// ---------------------------------------------------------------------------
// Fused prep: blocks [0,1024): s[b,c] = style.modw^T*lin + bias
//             blocks [1024,2048): ssq[o,c] = sum_tap w^2
__global__ __launch_bounds__(256) void k_prep1(const float* __restrict__ style,
                                               const float* __restrict__ modw,
                                               const float* __restrict__ modb,
                                               const float* __restrict__ weight,
                                               float* __restrict__ s_buf,
                                               float* __restrict__ ssq) {
  int tid = threadIdx.x;
  if (blockIdx.x < 1024) {
    int lane = tid & 63, wv = tid >> 6;
    int idx = blockIdx.x * 4 + wv; // [0,4096)
    int b = idx >> 9, c = idx & 511;
    const float* st = style + b * 512;
    const float* mw = modw + (size_t)c * 512;
    float s = 0.f;
#pragma unroll
    for (int i = 0; i < 8; ++i) s += st[lane + i * 64] * mw[lane + i * 64];
#pragma unroll
    for (int off = 32; off; off >>= 1) s += __shfl_xor(s, off);
    if (lane == 0) s_buf[idx] = s * kLinScale + modb[c];
  } else {
    int e = (blockIdx.x - 1024) * 256 + tid; // [0, 262144)
    const float* wp = weight + (size_t)e * 9;
    float ss = 0.f;
#pragma unroll
    for (int t = 0; t < 9; ++t) ss += wp[t] * wp[t];
    ssq[e] = ss;
  }
}

// ---------------------------------------------------------------------------
// Fused stage 2 (one launch instead of three):
//   blocks [0,4096):      NCHW f32 -> NHWC bf16 transpose with modulation
//   blocks [4096,4608):   weight fragment repack (batch-independent)
//   blocks [4608,5632):   demod[b,o] = rsqrt(kScale^2*sum ssq*s^2 + eps)
// Branch bodies are byte-identical to the previous k_transpose / k_wfrag /
// k_demod2; only the block-index decode changed. Tests whether the stable
// ~120 us total-minus-conv gap is real pre-kernel/launch-gap time.
__global__ __launch_bounds__(256) void k_fused2(const float* __restrict__ in,
                                                const float* __restrict__ s_buf,
                                                const float* __restrict__ weight,
                                                const float* __restrict__ ssq,
                                                unsigned* __restrict__ in_t32,
                                                unsigned* __restrict__ wt32,
                                                float* __restrict__ demod_buf) {
  __shared__ char shm[9216];
  int tid = threadIdx.x;
  int bid = blockIdx.x;
  if (bid < 4096) {
    // ---- transpose: bid = c0g + 8*y + 512*b ----
    u16* tile = (u16*)shm; // [64*65] u16 = 8320 B
    int c0 = (bid & 7) * 64, y = (bid >> 3) & 63, b = bid >> 9;
    const float* src = in + ((size_t)(b * 512 + c0) * 4096) + y * 64;
    const float* srow = s_buf + b * 512 + c0;
#pragma unroll
    for (int it = 0; it < 16; ++it) {
      int idx = it * 256 + tid;
      int cl = idx >> 6, x = idx & 63;
      tile[cl * 65 + x] = f2bf(src[(size_t)cl * 4096 + x] * srow[cl]);
    }
    __syncthreads();
    unsigned* dst = in_t32 + ((size_t)(b * 64 + y) * 64) * 256 + (c0 >> 1);
#pragma unroll
    for (int it = 0; it < 8; ++it) {
      int flat = it * 256 + tid; // [0,2048)
      int cl2 = flat & 31, x = flat >> 5;
      unsigned lo = tile[(2 * cl2) * 65 + x];
      unsigned hi = tile[(2 * cl2 + 1) * 65 + x];
      dst[(size_t)x * 256 + cl2] = lo | (hi << 16);
    }
  } else if (bid < 4608) {
    // ---- wfrag: w = bid-4096; ct = w&15, ot = w>>4 ----
    u16(*tiles)[512] = (u16(*)[512])shm; // [9][512] u16 = 9216 B
    int w = bid - 4096;
    int ct = w & 15, ot = w >> 4;
    int o0 = ot * 16, c0 = ct * 32;
#pragma unroll
    for (int i = 0; i < 18; ++i) {
      int flat = i * 256 + tid;       // [0,4608) = o_l*288 + c_l*9 + tap
      int t9 = flat / 9;
      int tap = flat - t9 * 9;
      int o_l = t9 >> 5, c_l = t9 & 31;
      float wt = weight[((size_t)(o0 + o_l) * 512 + c0 + c_l) * 9 + tap];
      int pos = ((o_l + ((c_l >> 3) << 4)) << 3) + (c_l & 7);
      tiles[tap][pos] = f2bf(wt * kScale);
    }
    __syncthreads();
    const unsigned* tl = (const unsigned*)tiles;
#pragma unroll
    for (int tap = 0; tap < 9; ++tap)
      wt32[(size_t)((tap * 16 + ct) * 32 + ot) * 256 + tid] = tl[tap * 256 + tid];
  } else {
    // ---- demod: idx = (bid-4608)*4 + wave ----
    int lane = tid & 63, wv = tid >> 6;
    int idx = (bid - 4608) * 4 + wv; // [0,4096)
    int b = idx >> 9, o = idx & 511;
    const float* sq = ssq + (size_t)o * 512;
    const float* srow = s_buf + b * 512;
    float ss = 0.f;
#pragma unroll
    for (int i = 0; i < 8; ++i) {
      float s = srow[lane + i * 64];
      ss += sq[lane + i * 64] * s * s;
    }
#pragma unroll
    for (int off = 32; off; off >>= 1) ss += __shfl_xor(ss, off);
    if (lane == 0) demod_buf[idx] = rsqrtf(ss * kScale2 + 1e-8f);
  }
}

// ---------------------------------------------------------------------------
// Implicit-GEMM conv — R6 champion, byte-identical (127 us, MfmaUtil 56%,
// zero bank conflicts). K=64 per t-step, double-buffered 64-ch B cells with
// the PROVEN 64B-cell 8-slot swizzle (slot = chunk8 ^ (x&7); odd/even cells
// hit disjoint bank halves), depth-1 A/B register rings, counted vmcnt(8)
// barrier, XCD swizzle lin&7 = batch.
__global__ __launch_bounds__(256, 2) void k_conv(const u16* __restrict__ in_t,
                                                 const u16* __restrict__ w_t,
                                                 const float* __restrict__ demod_buf,
                                                 float* __restrict__ out) {
  __shared__ char smem[67584]; // 2 buffers x (4 rows x 66 cells x 128 B)
  const int tid = threadIdx.x;
  const int lane = tid & 63;
  const int wv = tid >> 6;
  const int wm = wv >> 1, wn = wv & 1;
  const int quad = lane >> 4, m16 = lane & 15;
  const int lin = blockIdx.x + 32 * blockIdx.y + 128 * blockIdx.z; // [0,1024)
  const int b = lin & 7;
  const int r_ = lin >> 3;   // [0,128)
  const int nt = r_ & 31;
  const int mt = r_ >> 5;    // [0,4)
  const int y0 = nt * 2;

  floatx4 acc[4][4];
#pragma unroll
  for (int i = 0; i < 4; ++i)
#pragma unroll
    for (int j = 0; j < 4; ++j) acc[i][j] = (floatx4){0.f, 0.f, 0.f, 0.f};

  // per-lane A base (u16); A frag ms of (tap, ct32) at
  // abase + ((tap*16 + ct32)<<14) + ms*512, ct32 = 2*ct' + kh
  const u16* abase = w_t + mt * 4096 + wm * 2048 + lane * 8;

  // B stage source: thread covers slot chunk of cell xs (h=0: x 0..31;
  // h=1 adds +16384 u16 = +32 cells). Inverse swizzle on the source.
  const int xs = tid >> 3, qs = tid & 7;
  const int cch = qs ^ (xs & 7); // global 8-ch chunk stored at slot qs
  const u16* gB[4];
  bool rok[4];
#pragma unroll
  for (int r = 0; r < 4; ++r) {
    int y = y0 - 1 + r;
    rok[r] = (unsigned)y < 64u; // block-uniform
    gB[r] = in_t + (((size_t)(b * 64 + (rok[r] ? y : 0)) * 64 + xs) * 512 + cch * 8);
  }

  // B read bases, one per (dx, kh). row=(wn+dy):
  // addr = row*8448 + (sx+1)*128 + ((kh*4+quad)^(sx&7))*16,
  // sx = ns*16+m16+dx-1; ns-step = +2048 (slot invariant), dy-step = +8448.
  char* bA[6];
#pragma unroll
  for (int dx = 0; dx < 3; ++dx) {
    const int sx0 = m16 + dx - 1;
#pragma unroll
    for (int kh = 0; kh < 2; ++kh)
      bA[dx * 2 + kh] = smem + wn * 8448 + (sx0 + 1) * 128 +
                        (((kh * 4 + quad) ^ (sx0 & 7)) << 4);
  }

  bf16x8 aR[2][2][4];
  bf16x8 bv[2][2][4];

#define LOAD_BV(si, bufimm, t_)                                              \
  {                                                                          \
    const int dy_ = (t_) / 3, dx_ = (t_) % 3;                                \
    _Pragma("unroll") for (int kh = 0; kh < 2; ++kh)                         \
      _Pragma("unroll") for (int ns = 0; ns < 4; ++ns)                       \
        bv[si][kh][ns] = *(const bf16x8*)(bA[dx_ * 2 + kh] + (bufimm) +      \
                                          dy_ * 8448 + ns * 2048);           \
  }

#define STAGE_B(bufimm)                                                      \
  {                                                                          \
    _Pragma("unroll") for (int r = 0; r < 4; ++r)                            \
      if (rok[r]) {                                                          \
        GLD16(gB[r], smem + (bufimm) + r * 8448 + 128 + wv * 1024);          \
        GLD16(gB[r] + 16384,                                                 \
              smem + (bufimm) + r * 8448 + 128 + 4096 + wv * 1024);          \
      }                                                                      \
  }

#define LOAD_A2(si, tp_, ctp_)                                               \
  {                                                                          \
    _Pragma("unroll") for (int kh = 0; kh < 2; ++kh) {                       \
      const u16* ap_ =                                                       \
          abase + ((size_t)((tp_)*16 + 2 * (ctp_) + kh) << 14);              \
      _Pragma("unroll") for (int ms = 0; ms < 4; ++ms)                       \
        aR[si][kh][ms] = *(const bf16x8*)(ap_ + ms * 512);                   \
    }                                                                        \
  }

// one ct' (64 channels): 9 tap-steps of 32 MFMA; A+B frag prefetch depth 1;
// stage(ct'+1) in flight across the whole t-loop, drained by vmcnt(8).
#define CT_BODY(ctv, par, CURIMM, NXTIMM)                                    \
  {                                                                          \
    LOAD_BV(par, CURIMM, 0);                                                 \
    if ((ctv) + 1 < 8) {                                                     \
      _Pragma("unroll") for (int r = 0; r < 4; ++r) gB[r] += 64;             \
      STAGE_B(NXTIMM);                                                       \
    }                                                                        \
    _Pragma("unroll") for (int t = 0; t < 9; ++t) {                          \
      const int icur = (t + (par)) & 1;                                      \
      const int inxt = icur ^ 1;                                             \
      const int tp = t < 8 ? t + 1 : 0;                                      \
      const int ctp = t < 8 ? (ctv) : (ctv) + 1;                             \
      LOAD_A2(inxt, tp, ctp);                                                \
      if (t < 8) { LOAD_BV(inxt, CURIMM, t + 1); }                           \
      __builtin_amdgcn_s_setprio(1);                                         \
      _Pragma("unroll") for (int kh = 0; kh < 2; ++kh)                       \
        _Pragma("unroll") for (int ns = 0; ns < 4; ++ns)                     \
          _Pragma("unroll") for (int ms = 0; ms < 4; ++ms)                   \
            acc[ms][ns] = __builtin_amdgcn_mfma_f32_16x16x32_bf16(           \
                aR[icur][kh][ms], bv[icur][kh][ns], acc[ms][ns], 0, 0, 0);   \
      __builtin_amdgcn_s_setprio(0);                                         \
    }                                                                        \
    asm volatile("s_waitcnt vmcnt(8)" ::: "memory");                         \
    __builtin_amdgcn_s_barrier();                                            \
  }

  // ---- prologue: zero LDS (pads + OOB rows), stage ct'=0, load A(0, 0|1) --
  {
    const uint4 z = make_uint4(0u, 0u, 0u, 0u);
    for (int i = tid; i < 4224; i += 256) ((uint4*)smem)[i] = z;
  }
  __syncthreads();
  STAGE_B(0);
  __syncthreads(); // drains stage(0) + makes zeros visible
  LOAD_A2(0, 0, 0);

  for (int ct = 0; ct < 8; ct += 2) {
    CT_BODY(ct, 0, 0, 33792);
    CT_BODY(ct + 1, 1, 33792, 0);
  }

#undef LOAD_BV
#undef STAGE_B
#undef LOAD_A2
#undef CT_BODY

  // epilogue: D[m=quad*4+r][n=lane&15], scale by demod[b,o], f32 out
  const int ob = mt * 128 + wm * 64;
  const int nb = nt * 128 + wn * 64;
#pragma unroll
  for (int ms = 0; ms < 4; ++ms)
#pragma unroll
    for (int ns = 0; ns < 4; ++ns) {
      const int n = nb + ns * 16 + m16;
#pragma unroll
      for (int r = 0; r < 4; ++r) {
        const int o = ob + ms * 16 + quad * 4 + r;
        float dm = demod_buf[b * 512 + o];
        out[((size_t)(b * 512 + o) << 12) + n] = acc[ms][ns][r] * dm;
      }
    }
}

// ---------------------------------------------------------------------------
extern "C" void kernel_launch(void* const* d_in, const int* in_sizes, int n_in,
                              void* d_out, int out_size, void* d_ws, size_t ws_size,
                              hipStream_t stream) {
  const float* input = (const float*)d_in[0];   // [8,512,64,64] f32
  const float* style = (const float*)d_in[1];   // [8,512] f32
  const float* weight = (const float*)d_in[2];  // [1,512,512,3,3] f32
  const float* modw = (const float*)d_in[3];    // [512,512] f32
  const float* modb = (const float*)d_in[4];    // [512] f32
  float* out = (float*)d_out;                   // [8,512,64,64] f32
  char* ws = (char*)d_ws;
  float* s_buf = (float*)ws;                             // 16 KB
  float* demod_buf = (float*)(ws + 16384);               // 16 KB
  float* ssq = (float*)(ws + 32768);                     // 1 MB
  u16* in_t = (u16*)(ws + 32768 + 1048576);              // NHWC bf16, 33.5 MB
  u16* w_t = (u16*)(ws + 32768 + 1048576 + 33554432);    // frag bf16, 4.7 MB

  k_prep1<<<dim3(2048), dim3(256), 0, stream>>>(style, modw, modb, weight, s_buf, ssq);
  k_fused2<<<dim3(5632), dim3(256), 0, stream>>>(input, s_buf, weight, ssq,
                                                 (unsigned*)in_t, (unsigned*)w_t,
                                                 demod_buf);
  k_conv<<<dim3(32, 4, 8), dim3(256), 0, stream>>>(in_t, w_t, demod_buf, out);
}